// Round 15
// baseline (648.122 us; speedup 1.0000x reference)
//
#include <hip/hip_runtime.h>
#include <hip/hip_bf16.h>

// Problem dims
#define NNODE 32
#define NB    64
#define NDIM  32
#define NSTEP 8
#define NE    992
#define NTT   16

typedef __bf16 bf16;
typedef __attribute__((ext_vector_type(8))) __bf16 bf16x8;
typedef __attribute__((ext_vector_type(4))) __bf16 bf16x4;
typedef __attribute__((ext_vector_type(4))) float  f32x4;

__device__ __forceinline__ f32x4 mfma_bf16(bf16x8 a, bf16x8 b, f32x4 c) {
  return __builtin_amdgcn_mfma_f32_16x16x32_bf16(a, b, c, 0, 0, 0);
}
__device__ __forceinline__ float sigm(float x) { return 1.0f / (1.0f + __expf(-x)); }
__device__ __forceinline__ float tanh_f(float x) {
  x = fminf(fmaxf(x, -15.0f), 15.0f);
  float e = __expf(2.0f * x);
  return (e - 1.0f) / (e + 1.0f);
}

// ---------------------------------------------------------------------------
// Swizzle all weights into MFMA B-fragment bf16 order (round-3 validated).
// ---------------------------------------------------------------------------
__global__ void prep_weights(
    const float* __restrict__ msgW1, const float* __restrict__ msgW2,
    const float* __restrict__ geWi,  const float* __restrict__ geWh,
    const float* __restrict__ gnWi,  const float* __restrict__ gnWh,
    const float* __restrict__ oW1,   const float* __restrict__ oW2,
    const float* __restrict__ oW3,
    bf16* __restrict__ B1, bf16* __restrict__ B2,
    bf16* __restrict__ GI, bf16* __restrict__ GH,
    bf16* __restrict__ GN,
    bf16* __restrict__ OW1s, bf16* __restrict__ OW2s, bf16* __restrict__ OW3s) {
  int u = blockIdx.x * 256 + threadIdx.x;
  if (u < 12288) {
    int k = u >> 12, i = (u >> 6) & 63, h = u & 63;
    int kf = i >> 5, quad = (i >> 3) & 3, j = i & 7;
    int nn = k * 64 + h, nt = nn >> 4, lane = quad * 16 + (nn & 15);
    int slot = ((nt * 2 + kf) * 64 + lane) * 8 + j;
    B1[slot] = (bf16)msgW1[u];
    GI[slot] = (bf16)geWi[u];
    GH[slot] = (bf16)geWh[u];
    int ntl = h >> 4, lane2 = quad * 16 + (h & 15);
    int slot2 = k * 4096 + ((ntl * 2 + kf) * 64 + lane2) * 8 + j;
    B2[slot2] = (bf16)msgW2[u];
  } else if (u < 39936) {
    int v = u - 12288;
    int kk = v / 9216, rem = v % 9216, i = rem / 96, h = rem % 96;
    int kf = i >> 5, loc = i & 31, quad = loc >> 3, j = loc & 7;
    int nn = kk * 96 + h, nt = nn >> 4, lane = quad * 16 + (nn & 15);
    int slot = ((nt * 3 + kf) * 64 + lane) * 8 + j;
    GN[slot]         = (bf16)gnWi[v];
    GN[27648 + slot] = (bf16)gnWh[v];
  } else if (u < 46080) {
    int v = u - 39936; int i = v >> 6, h = v & 63;
    int kf = i >> 5, loc = i & 31, quad = loc >> 3, j = loc & 7;
    int nt = h >> 4, lane = quad * 16 + (h & 15);
    OW1s[((nt * 3 + kf) * 64 + lane) * 8 + j] = (bf16)oW1[v];
  } else if (u < 50176) {
    int v = u - 46080; int i = v >> 6, h = v & 63;
    int kf = i >> 5, quad = (i >> 3) & 3, j = i & 7;
    int nt = h >> 4, lane = quad * 16 + (h & 15);
    OW2s[((nt * 2 + kf) * 64 + lane) * 8 + j] = (bf16)oW2[v];
  } else if (u < 52224) {
    int v = u - 50176; int i = v >> 5, h = v & 31;
    int kf = i >> 5, quad = (i >> 3) & 3, j = i & 7;
    int nt = h >> 4, lane = quad * 16 + (h & 15);
    OW3s[((nt * 2 + kf) * 64 + lane) * 8 + j] = (bf16)oW3[v];
  }
}

// xf = fp32 x[...,0] in [n][b][d]; xball[t] = bf16 x[...,t] for t=0..7.
__global__ void copy_x(const float* __restrict__ x, float* __restrict__ xf,
                       bf16* __restrict__ xball) {
  int u = blockIdx.x * 256 + threadIdx.x;  // 65536
  int n = u >> 11, b = (u >> 5) & 63, d = u & 31;
  int base = ((b * 32 + n) * 32 + d) * 8;
  xf[u] = x[base];
#pragma unroll
  for (int t = 0; t < 8; t++)
    xball[t * 65536 + u] = (bf16)x[base + t];
}

// ---------------------------------------------------------------------------
// Edge body v11: R10 structure but Hh LDS stage dropped -> LDS 52736 B ->
// 3 blocks/CU (24 waves/CU, +50% TLP). GRU reads old state directly from
// global hedR (the pre-R7 pattern); more resident independent blocks now
// cover that latency. VGPR 64 <= 85 cap of launch_bounds(512,6).
// smem: scrbuf[51200] | zL 1536 = 52736 B.
// ---------------------------------------------------------------------------
__device__ __forceinline__ void edge_body(
    char* smem, int e0, int tid,
    const bf16* __restrict__ xsrc, const int* __restrict__ es,
    const float* __restrict__ z,
    const bf16* __restrict__ B1, const bf16* __restrict__ B2,
    const float* __restrict__ mb1, const float* __restrict__ mb2,
    const bf16* __restrict__ GI, const bf16* __restrict__ GH,
    const float* __restrict__ gbi, const float* __restrict__ gbh,
    const bf16* __restrict__ hedR, bf16* __restrict__ hedW, int t) {
  char* scrbuf = smem;
  float (*zL)[64][3] = (float(*)[64][3])(smem + 51200);
  bf16 (*A)[64][72]   = (bf16(*)[64][72])scrbuf;    // mix state (t>0 handoff)
  bf16 (*A2)[64][200] = (bf16(*)[64][200])scrbuf;   // h1 (aliases A)

  int c0_ = es[e0],     r0 = es[NE + e0];
  int c1_ = es[e0 + 1], r1 = es[NE + e0 + 1];
  int wv = tid >> 6, ln = tid & 63, quad = ln >> 4, l16 = ln & 15;
  int rg = wv & 3, cg = wv >> 2;       // row-group 0..3, col-group 0..1
  int m = rg * 16 + l16;

  // ---- entry staging: z (latency overlaps af + L1) ----
  for (int u = tid; u < 384; u += 512) {
    int pe = u / 192, rem = u % 192, b = rem / 3, k = rem % 3;
    zL[pe][b][k] = z[(b * NE + e0 + pe) * 3 + k];
  }

  // ---- A-fragments direct from global ----
  bf16x8 af[2][2];
  af[0][0] = *(const bf16x8*)(xsrc + r0 * 2048 + m * 32 + quad * 8);
  af[0][1] = *(const bf16x8*)(xsrc + c0_ * 2048 + m * 32 + quad * 8);
  af[1][0] = *(const bf16x8*)(xsrc + r1 * 2048 + m * 32 + quad * 8);
  af[1][1] = *(const bf16x8*)(xsrc + c1_ * 2048 + m * 32 + quad * 8);

  // ---- layer 1 ----
  f32x4 acc1[2][6];
#pragma unroll
  for (int pe = 0; pe < 2; pe++)
#pragma unroll
    for (int q = 0; q < 6; q++) { f32x4 zz = {0.f,0.f,0.f,0.f}; acc1[pe][q] = zz; }
#pragma unroll
  for (int j = 0; j < 6; j++) {
    int nt = cg * 6 + j;
    bf16x8 w0 = *(const bf16x8*)&B1[(nt * 2 + 0) * 512 + ln * 8];
    bf16x8 w1 = *(const bf16x8*)&B1[(nt * 2 + 1) * 512 + ln * 8];
#pragma unroll
    for (int pe = 0; pe < 2; pe++) {
      acc1[pe][j] = mfma_bf16(af[pe][0], w0, acc1[pe][j]);
      acc1[pe][j] = mfma_bf16(af[pe][1], w1, acc1[pe][j]);
    }
  }
#pragma unroll
  for (int j = 0; j < 6; j++) {
    int nt = cg * 6 + j;
    int n = nt * 16 + l16;
    float bias = mb1[n];
#pragma unroll
    for (int pe = 0; pe < 2; pe++)
#pragma unroll
      for (int r = 0; r < 4; r++) {
        float v = acc1[pe][j][r] + bias;
        A2[pe][rg * 16 + quad * 4 + r][n] = (bf16)(v > 0.f ? v : 0.f);
      }
  }
  __syncthreads();  // #1: A2 ready
  // ---- layer 2 ----
  f32x4 acc2[2][3][2];
#pragma unroll
  for (int pe = 0; pe < 2; pe++)
#pragma unroll
    for (int kt = 0; kt < 3; kt++)
#pragma unroll
      for (int oi = 0; oi < 2; oi++) { f32x4 zz = {0.f,0.f,0.f,0.f}; acc2[pe][kt][oi] = zz; }
#pragma unroll
  for (int kt = 0; kt < 3; kt++) {
    bf16x8 a2f[2][2];
#pragma unroll
    for (int pe = 0; pe < 2; pe++)
#pragma unroll
      for (int kf = 0; kf < 2; kf++)
        a2f[pe][kf] = *(const bf16x8*)&A2[pe][m][kt * 64 + kf * 32 + quad * 8];
#pragma unroll
    for (int oi = 0; oi < 2; oi++) {
      int ot = cg * 2 + oi;
      bf16x8 w0 = *(const bf16x8*)&B2[kt * 4096 + (ot * 2 + 0) * 512 + ln * 8];
      bf16x8 w1 = *(const bf16x8*)&B2[kt * 4096 + (ot * 2 + 1) * 512 + ln * 8];
#pragma unroll
      for (int pe = 0; pe < 2; pe++) {
        acc2[pe][kt][oi] = mfma_bf16(a2f[pe][0], w0, acc2[pe][kt][oi]);
        acc2[pe][kt][oi] = mfma_bf16(a2f[pe][1], w1, acc2[pe][kt][oi]);
      }
    }
  }
  __syncthreads();  // #2: A2 dead -> A may overwrite
  // ---- mix with z, /K ----
  float mb2v[3][2];
#pragma unroll
  for (int kt = 0; kt < 3; kt++)
#pragma unroll
    for (int oi = 0; oi < 2; oi++)
      mb2v[kt][oi] = mb2[kt * 64 + (cg * 2 + oi) * 16 + l16];
#pragma unroll
  for (int pe = 0; pe < 2; pe++)
#pragma unroll
    for (int r = 0; r < 4; r++) {
      int b = rg * 16 + quad * 4 + r;
      float z0 = zL[pe][b][0], z1 = zL[pe][b][1], z2 = zL[pe][b][2];
#pragma unroll
      for (int oi = 0; oi < 2; oi++) {
        int o = (cg * 2 + oi) * 16 + l16;
        float h0 = acc2[pe][0][oi][r] + mb2v[0][oi]; h0 = h0 > 0.f ? h0 : 0.f;
        float h1 = acc2[pe][1][oi][r] + mb2v[1][oi]; h1 = h1 > 0.f ? h1 : 0.f;
        float h2 = acc2[pe][2][oi][r] + mb2v[2][oi]; h2 = h2 > 0.f ? h2 : 0.f;
        float val = (h0 * z0 + h1 * z1 + h2 * z2) * (1.0f / 3.0f);
        if (t == 0)
          hedW[(e0 + pe) * 4096 + b * 64 + o] = (bf16)val;
        else
          A[pe][b][o] = (bf16)val;
      }
    }
  if (t > 0) {
    // old-state fragments direct from global (latency overlaps barrier #3)
    bf16x8 ah[2][2];
#pragma unroll
    for (int pe = 0; pe < 2; pe++) {
      const bf16* hrow = hedR + (e0 + pe) * 4096 + m * 64;
      ah[pe][0] = *(const bf16x8*)(hrow + quad * 8);
      ah[pe][1] = *(const bf16x8*)(hrow + 32 + quad * 8);
    }
    __syncthreads();  // #3: mix ready
    bf16x8 ai[2][2];
#pragma unroll
    for (int pe = 0; pe < 2; pe++)
#pragma unroll
      for (int kf = 0; kf < 2; kf++)
        ai[pe][kf] = *(const bf16x8*)&A[pe][m][kf * 32 + quad * 8];
#pragma unroll
    for (int oi = 0; oi < 2; oi++) {
      int ot = cg * 2 + oi;
      f32x4 gr[2], gi2[2], gni2[2], gnh2[2];
#pragma unroll
      for (int pe = 0; pe < 2; pe++) {
        f32x4 zz = {0.f,0.f,0.f,0.f};
        gr[pe] = zz; gi2[pe] = zz; gni2[pe] = zz; gnh2[pe] = zz;
      }
#pragma unroll
      for (int g = 0; g < 2; g++) {
        int nt = g * 4 + ot;
        bf16x8 wi0 = *(const bf16x8*)&GI[(nt * 2 + 0) * 512 + ln * 8];
        bf16x8 wi1 = *(const bf16x8*)&GI[(nt * 2 + 1) * 512 + ln * 8];
        bf16x8 wh0 = *(const bf16x8*)&GH[(nt * 2 + 0) * 512 + ln * 8];
        bf16x8 wh1 = *(const bf16x8*)&GH[(nt * 2 + 1) * 512 + ln * 8];
#pragma unroll
        for (int pe = 0; pe < 2; pe++) {
          f32x4 a = g ? gi2[pe] : gr[pe];
          a = mfma_bf16(ai[pe][0], wi0, a);
          a = mfma_bf16(ai[pe][1], wi1, a);
          a = mfma_bf16(ah[pe][0], wh0, a);
          a = mfma_bf16(ah[pe][1], wh1, a);
          if (g) gi2[pe] = a; else gr[pe] = a;
        }
      }
      {
        int nt = 8 + ot;
        bf16x8 wi0 = *(const bf16x8*)&GI[(nt * 2 + 0) * 512 + ln * 8];
        bf16x8 wi1 = *(const bf16x8*)&GI[(nt * 2 + 1) * 512 + ln * 8];
        bf16x8 wh0 = *(const bf16x8*)&GH[(nt * 2 + 0) * 512 + ln * 8];
        bf16x8 wh1 = *(const bf16x8*)&GH[(nt * 2 + 1) * 512 + ln * 8];
#pragma unroll
        for (int pe = 0; pe < 2; pe++) {
          gni2[pe] = mfma_bf16(ai[pe][0], wi0, gni2[pe]);
          gni2[pe] = mfma_bf16(ai[pe][1], wi1, gni2[pe]);
          gnh2[pe] = mfma_bf16(ah[pe][0], wh0, gnh2[pe]);
          gnh2[pe] = mfma_bf16(ah[pe][1], wh1, gnh2[pe]);
        }
      }
      int o = ot * 16 + l16;
      float bir = gbi[o],       bhr = gbh[o];
      float bii = gbi[64 + o],  bhi = gbh[64 + o];
      float bin = gbi[128 + o], bhn = gbh[128 + o];
#pragma unroll
      for (int pe = 0; pe < 2; pe++)
#pragma unroll
        for (int r = 0; r < 4; r++) {
          int b = rg * 16 + quad * 4 + r;
          float xr = gr[pe][r]   + bir + bhr;
          float xi = gi2[pe][r]  + bii + bhi;
          float xn = gni2[pe][r] + bin;
          float hn = gnh2[pe][r] + bhn;
          float rgt = sigm(xr);
          float ig  = sigm(xi);
          float ng  = tanh_f(xn + rgt * hn);
          float hv  = (float)hedR[(e0 + pe) * 4096 + b * 64 + o];
          hedW[(e0 + pe) * 4096 + b * 64 + o] =
              (bf16)((1.0f - ig) * ng + ig * hv);
        }
    }
  }
}

// ---------------------------------------------------------------------------
// Node body v2 (R14-validated): gate-aligned GRU, gates finished in registers.
// Works at 384 (solo) and 512 (fused) threads. smem carve = 30208 B.
// ---------------------------------------------------------------------------
__device__ __forceinline__ void node_body(
    char* smem, int nq, int tid,
    const float* __restrict__ x, const bf16* __restrict__ hed,
    float* __restrict__ xf, bf16* __restrict__ xb, float* __restrict__ hnode,
    const bf16* __restrict__ GN,
    const float* __restrict__ gnbi, const float* __restrict__ gnbh,
    const bf16* __restrict__ OW1, const float* __restrict__ ob1,
    const bf16* __restrict__ OW2, const float* __restrict__ ob2,
    const bf16* __restrict__ OW3, const float* __restrict__ ob3,
    float* __restrict__ out, int t) {
  float (*aggf)[64] = (float(*)[64])(smem);            // 4096
  float (*xinf)[32] = (float(*)[32])(smem + 4096);     // 2048
  float (*hvf)[96]  = (float(*)[96])(smem + 6144);     // 6144
  bf16  (*c0b)[112] = (bf16(*)[112])(smem + 12288);    // 3584
  bf16  (*hvb)[112] = (bf16(*)[112])(smem + 15872);    // 3584
  bf16  (*cnb)[112] = (bf16(*)[112])(smem + 19456);    // 3584
  bf16  (*s1b)[112] = (bf16(*)[112])(smem + 23040);    // 3584
  bf16  (*s2b)[112] = (bf16(*)[112])(smem + 26624);    // 3584 -> 30208
  int n = nq >> 2, q = nq & 3;
  int wv = tid >> 6, ln = tid & 63, quad = ln >> 4, l16 = ln & 15;
  if (tid < 256) {
    int r = tid >> 4, o4 = tid & 15;
    const bf16x4* bp = (const bf16x4*)hed + (size_t)n * 31 * 1024 + (q * 16 + r) * 16 + o4;
    float sx = 0.f, sy = 0.f, sz = 0.f, sw = 0.f;
#pragma unroll
    for (int e2 = 0; e2 < 31; e2++) {
      bf16x4 v = bp[e2 * 1024];
      sx += (float)v[0]; sy += (float)v[1]; sz += (float)v[2]; sw += (float)v[3];
    }
    const float inv = 1.0f / 31.0f;
    sx *= inv; sy *= inv; sz *= inv; sw *= inv;
    int o = o4 * 4;
    aggf[r][o] = sx; aggf[r][o + 1] = sy; aggf[r][o + 2] = sz; aggf[r][o + 3] = sw;
    c0b[r][32 + o] = (bf16)sx; c0b[r][33 + o] = (bf16)sy;
    c0b[r][34 + o] = (bf16)sz; c0b[r][35 + o] = (bf16)sw;
  }
  if (tid < 128) {
    int r = tid >> 3, d0 = (tid & 7) * 4;
    int b = q * 16 + r;
#pragma unroll
    for (int k = 0; k < 4; k++) {
      float v = xf[n * 2048 + b * 32 + d0 + k];
      xinf[r][d0 + k] = v;
      c0b[r][d0 + k] = (bf16)v;
    }
  }
  if (t > 0 && tid < 256) {
    int r = tid >> 4, cb = (tid & 15) * 6;
    int row = n * 64 + q * 16 + r;
#pragma unroll
    for (int k = 0; k < 6; k++) {
      float v = hnode[row * 96 + cb + k];
      hvf[r][cb + k] = v;
      hvb[r][cb + k] = (bf16)v;
    }
  }
  __syncthreads();
  if (t > 0 && wv < 6) {
    int ct = wv;
    bf16x8 a0[3], a1[3];
#pragma unroll
    for (int kf = 0; kf < 3; kf++) {
      a0[kf] = *(const bf16x8*)&c0b[l16][kf * 32 + quad * 8];
      a1[kf] = *(const bf16x8*)&hvb[l16][kf * 32 + quad * 8];
    }
    const bf16* W0 = GN;
    const bf16* W1 = GN + 27648;
    f32x4 aR = {0.f,0.f,0.f,0.f}, bR = {0.f,0.f,0.f,0.f};
    f32x4 aI = {0.f,0.f,0.f,0.f}, bI = {0.f,0.f,0.f,0.f};
    f32x4 aN = {0.f,0.f,0.f,0.f}, bN = {0.f,0.f,0.f,0.f};
#pragma unroll
    for (int kf = 0; kf < 3; kf++) {
      int ir = ((ct * 3 + kf) * 64 + ln) * 8;
      int ii = (((6 + ct) * 3 + kf) * 64 + ln) * 8;
      int in_ = (((12 + ct) * 3 + kf) * 64 + ln) * 8;
      aR = mfma_bf16(a0[kf], *(const bf16x8*)&W0[ir],  aR);
      bR = mfma_bf16(a1[kf], *(const bf16x8*)&W1[ir],  bR);
      aI = mfma_bf16(a0[kf], *(const bf16x8*)&W0[ii],  aI);
      bI = mfma_bf16(a1[kf], *(const bf16x8*)&W1[ii],  bI);
      aN = mfma_bf16(a0[kf], *(const bf16x8*)&W0[in_], aN);
      bN = mfma_bf16(a1[kf], *(const bf16x8*)&W1[in_], bN);
    }
    int col = ct * 16 + l16;
    float bRc = gnbi[col] + gnbh[col];
    float bIc = gnbi[96 + col] + gnbh[96 + col];
    float bN0 = gnbi[192 + col], bN1 = gnbh[192 + col];
    int rowbase = n * 64 + q * 16;
#pragma unroll
    for (int rr = 0; rr < 4; rr++) {
      int row = quad * 4 + rr;
      float xr = aR[rr] + bR[rr] + bRc;
      float xi = aI[rr] + bI[rr] + bIc;
      float xn = aN[rr] + bN0;
      float hn = bN[rr] + bN1;
      float rg = sigm(xr);
      float ig = sigm(xi);
      float ng = tanh_f(xn + rg * hn);
      float v = (1.0f - ig) * ng + ig * hvf[row][col];
      cnb[row][col] = (bf16)v;
      hnode[(rowbase + row) * 96 + col] = v;
    }
  }
  if (t == 0 && tid < 256) {
    int r = tid >> 4, cb = (tid & 15) * 6;
    int row = n * 64 + q * 16 + r;
#pragma unroll
    for (int k = 0; k < 6; k++) {
      int c = cb + k;
      float v = (c < 32) ? xinf[r][c] : aggf[r][c - 32];
      cnb[r][c] = (bf16)v;
      hnode[row * 96 + c] = v;
    }
  }
  __syncthreads();
  if (wv < 4) {
    bf16x8 af3[3];
#pragma unroll
    for (int kf = 0; kf < 3; kf++)
      af3[kf] = *(const bf16x8*)&cnb[l16][kf * 32 + quad * 8];
    f32x4 accn = {0.f, 0.f, 0.f, 0.f};
#pragma unroll
    for (int kf = 0; kf < 3; kf++) {
      bf16x8 bfrag = *(const bf16x8*)&OW1[((wv * 3 + kf) * 64 + ln) * 8];
      accn = mfma_bf16(af3[kf], bfrag, accn);
    }
    int col = wv * 16 + l16;
    float bias = ob1[col];
#pragma unroll
    for (int rr = 0; rr < 4; rr++) {
      float vv = accn[rr] + bias;
      s1b[quad * 4 + rr][col] = (bf16)(vv > 0.f ? vv : 0.f);
    }
  }
  __syncthreads();
  if (wv < 4) {
    bf16x8 af2[2];
#pragma unroll
    for (int kf = 0; kf < 2; kf++)
      af2[kf] = *(const bf16x8*)&s1b[l16][kf * 32 + quad * 8];
    f32x4 accn = {0.f, 0.f, 0.f, 0.f};
#pragma unroll
    for (int kf = 0; kf < 2; kf++) {
      bf16x8 bfrag = *(const bf16x8*)&OW2[((wv * 2 + kf) * 64 + ln) * 8];
      accn = mfma_bf16(af2[kf], bfrag, accn);
    }
    int col = wv * 16 + l16;
    float bias = ob2[col];
#pragma unroll
    for (int rr = 0; rr < 4; rr++) {
      float vv = accn[rr] + bias;
      s2b[quad * 4 + rr][col] = (bf16)(vv > 0.f ? vv : 0.f);
    }
  }
  __syncthreads();
  if (wv < 2) {
    bf16x8 af2[2];
#pragma unroll
    for (int kf = 0; kf < 2; kf++)
      af2[kf] = *(const bf16x8*)&s2b[l16][kf * 32 + quad * 8];
    f32x4 accn = {0.f, 0.f, 0.f, 0.f};
#pragma unroll
    for (int kf = 0; kf < 2; kf++) {
      bf16x8 bfrag = *(const bf16x8*)&OW3[((wv * 2 + kf) * 64 + ln) * 8];
      accn = mfma_bf16(af2[kf], bfrag, accn);
    }
    int d = wv * 16 + l16;
    float bias = ob3[d];
#pragma unroll
    for (int rr = 0; rr < 4; rr++) {
      int r = quad * 4 + rr;
      int b = q * 16 + r;
      float xm = xinf[r][d] + accn[rr] + bias;
      int base = (b * 32 + n) * 32 + d;
      out[524288 + base * 16 + t] = xm;
      out[1572864 + base * 16 + t] = xm;
      if (t >= NSTEP) out[base * 8 + (t - NSTEP)] = xm;
      float vnext = (t + 1 < NSTEP) ? x[base * 8 + (t + 1)] : xm;
      xf[n * 2048 + b * 32 + d] = vnext;
      xb[n * 2048 + b * 32 + d] = (bf16)vnext;
    }
  }
}

// ---------------------------------------------------------------------------
// Kernels: solo edge (3 blk/CU), solo node (384 thr), fused
// [node(t-1) || edge(t)] (t = 1..7). NO spin-gating (R11), NO fences (R2).
// ---------------------------------------------------------------------------
__global__ __launch_bounds__(512, 6) void edge_step(
    const bf16* __restrict__ xsrc, const int* __restrict__ es,
    const float* __restrict__ z,
    const bf16* __restrict__ B1, const bf16* __restrict__ B2,
    const float* __restrict__ mb1, const float* __restrict__ mb2,
    const bf16* __restrict__ GI, const bf16* __restrict__ GH,
    const float* __restrict__ gbi, const float* __restrict__ gbh,
    const bf16* __restrict__ hedR, bf16* __restrict__ hedW, int t) {
  __shared__ __align__(16) char smem[52736];
  edge_body(smem, blockIdx.x * 2, threadIdx.x, xsrc, es, z, B1, B2, mb1, mb2,
            GI, GH, gbi, gbh, hedR, hedW, t);
}

__global__ __launch_bounds__(384) void node_kernel(
    const float* __restrict__ x, const bf16* __restrict__ hed,
    float* __restrict__ xf, bf16* __restrict__ xb, float* __restrict__ hnode,
    const bf16* __restrict__ GN,
    const float* __restrict__ gnbi, const float* __restrict__ gnbh,
    const bf16* __restrict__ OW1, const float* __restrict__ ob1,
    const bf16* __restrict__ OW2, const float* __restrict__ ob2,
    const bf16* __restrict__ OW3, const float* __restrict__ ob3,
    float* __restrict__ out, int t) {
  __shared__ __align__(16) char smem[30208];
  node_body(smem, blockIdx.x, threadIdx.x, x, hed, xf, xb, hnode, GN,
            gnbi, gnbh, OW1, ob1, OW2, ob2, OW3, ob3, out, t);
}

__global__ __launch_bounds__(512, 6) void fused_ne(
    const float* __restrict__ x,
    const bf16* __restrict__ xsrc, const int* __restrict__ es,
    const float* __restrict__ z,
    const bf16* __restrict__ B1, const bf16* __restrict__ B2,
    const float* __restrict__ mb1, const float* __restrict__ mb2,
    const bf16* __restrict__ GI, const bf16* __restrict__ GH,
    const float* __restrict__ gbi, const float* __restrict__ gbh,
    const bf16* __restrict__ hedR, bf16* __restrict__ hedW,
    float* __restrict__ xf, bf16* __restrict__ xb, float* __restrict__ hnode,
    const bf16* __restrict__ GN,
    const float* __restrict__ gnbi, const float* __restrict__ gnbh,
    const bf16* __restrict__ OW1, const float* __restrict__ ob1,
    const bf16* __restrict__ OW2, const float* __restrict__ ob2,
    const bf16* __restrict__ OW3, const float* __restrict__ ob3,
    float* __restrict__ out, int te) {
  __shared__ __align__(16) char smem[52736];
  if (blockIdx.x < 128) {
    node_body(smem, blockIdx.x, threadIdx.x, x, hedR, xf, xb, hnode, GN,
              gnbi, gnbh, OW1, ob1, OW2, ob2, OW3, ob3, out, te - 1);
  } else {
    edge_body(smem, (blockIdx.x - 128) * 2, threadIdx.x, xsrc, es, z, B1, B2,
              mb1, mb2, GI, GH, gbi, gbh, hedR, hedW, te);
  }
}

extern "C" void kernel_launch(void* const* d_in, const int* in_sizes, int n_in,
                              void* d_out, int out_size, void* d_ws, size_t ws_size,
                              hipStream_t stream) {
  const float* x     = (const float*)d_in[0];
  const float* z     = (const float*)d_in[1];
  const int*   es    = (const int*)d_in[2];
  const float* msgW1 = (const float*)d_in[6];
  const float* msgb1 = (const float*)d_in[7];
  const float* msgW2 = (const float*)d_in[8];
  const float* msgb2 = (const float*)d_in[9];
  const float* oW1   = (const float*)d_in[10];
  const float* ob1   = (const float*)d_in[11];
  const float* oW2   = (const float*)d_in[12];
  const float* ob2   = (const float*)d_in[13];
  const float* oW3   = (const float*)d_in[14];
  const float* ob3   = (const float*)d_in[15];
  const float* geWi  = (const float*)d_in[16];
  const float* gebi  = (const float*)d_in[17];
  const float* geWh  = (const float*)d_in[18];
  const float* gebh  = (const float*)d_in[19];
  const float* gnWi  = (const float*)d_in[20];
  const float* gnbi  = (const float*)d_in[21];
  const float* gnWh  = (const float*)d_in[22];
  const float* gnbh  = (const float*)d_in[23];
  float* out = (float*)d_out;

  char* p = (char*)d_ws;
  bf16*  hedA  = (bf16*)p;   p += (size_t)NE * 4096 * 2;   // 8.1 MB
  bf16*  hedB  = (bf16*)p;   p += (size_t)NE * 4096 * 2;   // 8.1 MB
  bf16*  xball = (bf16*)p;   p += (size_t)8 * 65536 * 2;   // 1 MB
  float* xf    = (float*)p;  p += 65536 * 4;
  bf16*  xb    = (bf16*)p;   p += 65536 * 2;
  float* hnode = (float*)p;  p += 196608 * 4;
  bf16*  B1sw  = (bf16*)p;   p += 12288 * 2;
  bf16*  B2sw  = (bf16*)p;   p += 12288 * 2;
  bf16*  GIsw  = (bf16*)p;   p += 12288 * 2;
  bf16*  GHsw  = (bf16*)p;   p += 12288 * 2;
  bf16*  GNsw  = (bf16*)p;   p += 55296 * 2;
  bf16*  OW1s  = (bf16*)p;   p += 6144 * 2;
  bf16*  OW2s  = (bf16*)p;   p += 4096 * 2;
  bf16*  OW3s  = (bf16*)p;   p += 2048 * 2;

  bf16* hbuf[2] = {hedA, hedB};

  prep_weights<<<204, 256, 0, stream>>>(msgW1, msgW2, geWi, geWh, gnWi, gnWh,
                                        oW1, oW2, oW3,
                                        B1sw, B2sw, GIsw, GHsw, GNsw,
                                        OW1s, OW2s, OW3s);
  copy_x<<<256, 256, 0, stream>>>(x, xf, xball);

  // t = 0: edge only
  edge_step<<<NE / 2, 512, 0, stream>>>(xball, es, z, B1sw, B2sw, msgb1, msgb2,
                                        GIsw, GHsw, gebi, gebh,
                                        hbuf[1], hbuf[0], 0);
  // t = 1..7: fused [node(t-1) || edge(t)] — edge input is ground-truth x
  for (int t = 1; t < NSTEP; t++) {
    fused_ne<<<128 + NE / 2, 512, 0, stream>>>(
        x, xball + (size_t)t * 65536, es, z, B1sw, B2sw, msgb1, msgb2,
        GIsw, GHsw, gebi, gebh,
        hbuf[(t - 1) & 1], hbuf[t & 1],
        xf, xb, hnode, GNsw, gnbi, gnbh,
        OW1s, ob1, OW2s, ob2, OW3s, ob3, out, t);
  }
  // node(7) (produces xb for t=8), then serial for the feedback phase
  node_kernel<<<128, 384, 0, stream>>>(x, hbuf[(NSTEP - 1) & 1], xf, xb, hnode,
                                       GNsw, gnbi, gnbh, OW1s, ob1, OW2s, ob2,
                                       OW3s, ob3, out, NSTEP - 1);
  for (int t = NSTEP; t < NTT; t++) {
    edge_step<<<NE / 2, 512, 0, stream>>>(xb, es, z, B1sw, B2sw, msgb1, msgb2,
                                          GIsw, GHsw, gebi, gebh,
                                          hbuf[(t - 1) & 1], hbuf[t & 1], t);
    node_kernel<<<128, 384, 0, stream>>>(x, hbuf[t & 1], xf, xb, hnode,
                                         GNsw, gnbi, gnbh, OW1s, ob1, OW2s, ob2,
                                         OW3s, ob3, out, t);
  }
}

// Round 17
// 531.455 us; speedup vs baseline: 1.2195x; 1.2195x over previous
//
#include <hip/hip_runtime.h>
#include <hip/hip_bf16.h>

// Problem dims
#define NNODE 32
#define NB    64
#define NDIM  32
#define NSTEP 8
#define NE    992
#define NTT   16

typedef __bf16 bf16;
typedef __attribute__((ext_vector_type(8))) __bf16 bf16x8;
typedef __attribute__((ext_vector_type(4))) __bf16 bf16x4;
typedef __attribute__((ext_vector_type(4))) float  f32x4;

__device__ __forceinline__ f32x4 mfma_bf16(bf16x8 a, bf16x8 b, f32x4 c) {
  return __builtin_amdgcn_mfma_f32_16x16x32_bf16(a, b, c, 0, 0, 0);
}
__device__ __forceinline__ float sigm(float x) { return 1.0f / (1.0f + __expf(-x)); }
__device__ __forceinline__ float tanh_f(float x) {
  x = fminf(fmaxf(x, -15.0f), 15.0f);
  float e = __expf(2.0f * x);
  return (e - 1.0f) / (e + 1.0f);
}

// ---------------------------------------------------------------------------
// Swizzle all weights into MFMA B-fragment bf16 order (round-3 validated).
// ---------------------------------------------------------------------------
__global__ void prep_weights(
    const float* __restrict__ msgW1, const float* __restrict__ msgW2,
    const float* __restrict__ geWi,  const float* __restrict__ geWh,
    const float* __restrict__ gnWi,  const float* __restrict__ gnWh,
    const float* __restrict__ oW1,   const float* __restrict__ oW2,
    const float* __restrict__ oW3,
    bf16* __restrict__ B1, bf16* __restrict__ B2,
    bf16* __restrict__ GI, bf16* __restrict__ GH,
    bf16* __restrict__ GN,
    bf16* __restrict__ OW1s, bf16* __restrict__ OW2s, bf16* __restrict__ OW3s) {
  int u = blockIdx.x * 256 + threadIdx.x;
  if (u < 12288) {
    int k = u >> 12, i = (u >> 6) & 63, h = u & 63;
    int kf = i >> 5, quad = (i >> 3) & 3, j = i & 7;
    int nn = k * 64 + h, nt = nn >> 4, lane = quad * 16 + (nn & 15);
    int slot = ((nt * 2 + kf) * 64 + lane) * 8 + j;
    B1[slot] = (bf16)msgW1[u];
    GI[slot] = (bf16)geWi[u];
    GH[slot] = (bf16)geWh[u];
    int ntl = h >> 4, lane2 = quad * 16 + (h & 15);
    int slot2 = k * 4096 + ((ntl * 2 + kf) * 64 + lane2) * 8 + j;
    B2[slot2] = (bf16)msgW2[u];
  } else if (u < 39936) {
    int v = u - 12288;
    int kk = v / 9216, rem = v % 9216, i = rem / 96, h = rem % 96;
    int kf = i >> 5, loc = i & 31, quad = loc >> 3, j = loc & 7;
    int nn = kk * 96 + h, nt = nn >> 4, lane = quad * 16 + (nn & 15);
    int slot = ((nt * 3 + kf) * 64 + lane) * 8 + j;
    GN[slot]         = (bf16)gnWi[v];
    GN[27648 + slot] = (bf16)gnWh[v];
  } else if (u < 46080) {
    int v = u - 39936; int i = v >> 6, h = v & 63;
    int kf = i >> 5, loc = i & 31, quad = loc >> 3, j = loc & 7;
    int nt = h >> 4, lane = quad * 16 + (h & 15);
    OW1s[((nt * 3 + kf) * 64 + lane) * 8 + j] = (bf16)oW1[v];
  } else if (u < 50176) {
    int v = u - 46080; int i = v >> 6, h = v & 63;
    int kf = i >> 5, quad = (i >> 3) & 3, j = i & 7;
    int nt = h >> 4, lane = quad * 16 + (h & 15);
    OW2s[((nt * 2 + kf) * 64 + lane) * 8 + j] = (bf16)oW2[v];
  } else if (u < 52224) {
    int v = u - 50176; int i = v >> 5, h = v & 31;
    int kf = i >> 5, quad = (i >> 3) & 3, j = i & 7;
    int nt = h >> 4, lane = quad * 16 + (h & 15);
    OW3s[((nt * 2 + kf) * 64 + lane) * 8 + j] = (bf16)oW3[v];
  }
}

// xf = fp32 x[...,0] in [n][b][d]; xball[t] = bf16 x[...,t] for t=0..7.
__global__ void copy_x(const float* __restrict__ x, float* __restrict__ xf,
                       bf16* __restrict__ xball) {
  int u = blockIdx.x * 256 + threadIdx.x;  // 65536
  int n = u >> 11, b = (u >> 5) & 63, d = u & 31;
  int base = ((b * 32 + n) * 32 + d) * 8;
  xf[u] = x[base];
#pragma unroll
  for (int t = 0; t < 8; t++)
    xball[t * 65536 + u] = (bf16)x[base + t];
}

// ---------------------------------------------------------------------------
// Edge body (R10/R14-measured best, verbatim): direct-global af, direct
// biases, 3 barriers (t>0) / 2 (t=0), direct hed stores, entry-staged Hh
// (load-bearing: R15 showed removing it costs 21%).
// smem layout: scrbuf[51200] | zL 1536 | Hh 18432 = 71168 B. 2 blocks/CU.
// ---------------------------------------------------------------------------
__device__ __forceinline__ void edge_body(
    char* smem, int e0, int tid,
    const bf16* __restrict__ xsrc, const int* __restrict__ es,
    const float* __restrict__ z,
    const bf16* __restrict__ B1, const bf16* __restrict__ B2,
    const float* __restrict__ mb1, const float* __restrict__ mb2,
    const bf16* __restrict__ GI, const bf16* __restrict__ GH,
    const float* __restrict__ gbi, const float* __restrict__ gbh,
    const bf16* __restrict__ hedR, bf16* __restrict__ hedW, int t) {
  char* scrbuf = smem;
  float (*zL)[64][3] = (float(*)[64][3])(smem + 51200);
  bf16 (*Hh)[64][72] = (bf16(*)[64][72])(smem + 52736);
  bf16 (*A)[64][72]   = (bf16(*)[64][72])scrbuf;    // mix state (t>0 handoff)
  bf16 (*A2)[64][200] = (bf16(*)[64][200])scrbuf;   // h1 (aliases A)

  int c0_ = es[e0],     r0 = es[NE + e0];
  int c1_ = es[e0 + 1], r1 = es[NE + e0 + 1];
  int wv = tid >> 6, ln = tid & 63, quad = ln >> 4, l16 = ln & 15;
  int rg = wv & 3, cg = wv >> 2;       // row-group 0..3, col-group 0..1
  int m = rg * 16 + l16;

  // ---- entry staging: z and (t>0) old state. Latency overlaps af + L1. ----
  for (int u = tid; u < 384; u += 512) {
    int pe = u / 192, rem = u % 192, b = rem / 3, k = rem % 3;
    zL[pe][b][k] = z[(b * NE + e0 + pe) * 3 + k];
  }
  if (t > 0) {
    for (int u = tid; u < 1024; u += 512) {
      int pe = u >> 9, c = u & 511;
      int b = c >> 3, j = c & 7;
      *(bf16x8*)&Hh[pe][b][j * 8] =
          *(const bf16x8*)(hedR + (e0 + pe) * 4096 + b * 64 + j * 8);
    }
  }

  // ---- A-fragments direct from global ----
  bf16x8 af[2][2];
  af[0][0] = *(const bf16x8*)(xsrc + r0 * 2048 + m * 32 + quad * 8);
  af[0][1] = *(const bf16x8*)(xsrc + c0_ * 2048 + m * 32 + quad * 8);
  af[1][0] = *(const bf16x8*)(xsrc + r1 * 2048 + m * 32 + quad * 8);
  af[1][1] = *(const bf16x8*)(xsrc + c1_ * 2048 + m * 32 + quad * 8);

  // ---- layer 1 ----
  f32x4 acc1[2][6];
#pragma unroll
  for (int pe = 0; pe < 2; pe++)
#pragma unroll
    for (int q = 0; q < 6; q++) { f32x4 zz = {0.f,0.f,0.f,0.f}; acc1[pe][q] = zz; }
#pragma unroll
  for (int j = 0; j < 6; j++) {
    int nt = cg * 6 + j;
    bf16x8 w0 = *(const bf16x8*)&B1[(nt * 2 + 0) * 512 + ln * 8];
    bf16x8 w1 = *(const bf16x8*)&B1[(nt * 2 + 1) * 512 + ln * 8];
#pragma unroll
    for (int pe = 0; pe < 2; pe++) {
      acc1[pe][j] = mfma_bf16(af[pe][0], w0, acc1[pe][j]);
      acc1[pe][j] = mfma_bf16(af[pe][1], w1, acc1[pe][j]);
    }
  }
#pragma unroll
  for (int j = 0; j < 6; j++) {
    int nt = cg * 6 + j;
    int n = nt * 16 + l16;
    float bias = mb1[n];
#pragma unroll
    for (int pe = 0; pe < 2; pe++)
#pragma unroll
      for (int r = 0; r < 4; r++) {
        float v = acc1[pe][j][r] + bias;
        A2[pe][rg * 16 + quad * 4 + r][n] = (bf16)(v > 0.f ? v : 0.f);
      }
  }
  __syncthreads();  // #1: A2 ready; zL/Hh landed
  // ---- layer 2 ----
  f32x4 acc2[2][3][2];
#pragma unroll
  for (int pe = 0; pe < 2; pe++)
#pragma unroll
    for (int kt = 0; kt < 3; kt++)
#pragma unroll
      for (int oi = 0; oi < 2; oi++) { f32x4 zz = {0.f,0.f,0.f,0.f}; acc2[pe][kt][oi] = zz; }
#pragma unroll
  for (int kt = 0; kt < 3; kt++) {
    bf16x8 a2f[2][2];
#pragma unroll
    for (int pe = 0; pe < 2; pe++)
#pragma unroll
      for (int kf = 0; kf < 2; kf++)
        a2f[pe][kf] = *(const bf16x8*)&A2[pe][m][kt * 64 + kf * 32 + quad * 8];
#pragma unroll
    for (int oi = 0; oi < 2; oi++) {
      int ot = cg * 2 + oi;
      bf16x8 w0 = *(const bf16x8*)&B2[kt * 4096 + (ot * 2 + 0) * 512 + ln * 8];
      bf16x8 w1 = *(const bf16x8*)&B2[kt * 4096 + (ot * 2 + 1) * 512 + ln * 8];
#pragma unroll
      for (int pe = 0; pe < 2; pe++) {
        acc2[pe][kt][oi] = mfma_bf16(a2f[pe][0], w0, acc2[pe][kt][oi]);
        acc2[pe][kt][oi] = mfma_bf16(a2f[pe][1], w1, acc2[pe][kt][oi]);
      }
    }
  }
  __syncthreads();  // #2: A2 dead -> A may overwrite
  // ---- mix with z, /K ----
  float mb2v[3][2];
#pragma unroll
  for (int kt = 0; kt < 3; kt++)
#pragma unroll
    for (int oi = 0; oi < 2; oi++)
      mb2v[kt][oi] = mb2[kt * 64 + (cg * 2 + oi) * 16 + l16];
#pragma unroll
  for (int pe = 0; pe < 2; pe++)
#pragma unroll
    for (int r = 0; r < 4; r++) {
      int b = rg * 16 + quad * 4 + r;
      float z0 = zL[pe][b][0], z1 = zL[pe][b][1], z2 = zL[pe][b][2];
#pragma unroll
      for (int oi = 0; oi < 2; oi++) {
        int o = (cg * 2 + oi) * 16 + l16;
        float h0 = acc2[pe][0][oi][r] + mb2v[0][oi]; h0 = h0 > 0.f ? h0 : 0.f;
        float h1 = acc2[pe][1][oi][r] + mb2v[1][oi]; h1 = h1 > 0.f ? h1 : 0.f;
        float h2 = acc2[pe][2][oi][r] + mb2v[2][oi]; h2 = h2 > 0.f ? h2 : 0.f;
        float val = (h0 * z0 + h1 * z1 + h2 * z2) * (1.0f / 3.0f);
        if (t == 0)
          hedW[(e0 + pe) * 4096 + b * 64 + o] = (bf16)val;
        else
          A[pe][b][o] = (bf16)val;
      }
    }
  if (t > 0) {
    __syncthreads();  // #3: mix ready
    bf16x8 ai[2][2], ah[2][2];
#pragma unroll
    for (int pe = 0; pe < 2; pe++)
#pragma unroll
      for (int kf = 0; kf < 2; kf++) {
        ai[pe][kf] = *(const bf16x8*)&A[pe][m][kf * 32 + quad * 8];
        ah[pe][kf] = *(const bf16x8*)&Hh[pe][m][kf * 32 + quad * 8];
      }
#pragma unroll
    for (int oi = 0; oi < 2; oi++) {
      int ot = cg * 2 + oi;
      f32x4 gr[2], gi2[2], gni2[2], gnh2[2];
#pragma unroll
      for (int pe = 0; pe < 2; pe++) {
        f32x4 zz = {0.f,0.f,0.f,0.f};
        gr[pe] = zz; gi2[pe] = zz; gni2[pe] = zz; gnh2[pe] = zz;
      }
#pragma unroll
      for (int g = 0; g < 2; g++) {
        int nt = g * 4 + ot;
        bf16x8 wi0 = *(const bf16x8*)&GI[(nt * 2 + 0) * 512 + ln * 8];
        bf16x8 wi1 = *(const bf16x8*)&GI[(nt * 2 + 1) * 512 + ln * 8];
        bf16x8 wh0 = *(const bf16x8*)&GH[(nt * 2 + 0) * 512 + ln * 8];
        bf16x8 wh1 = *(const bf16x8*)&GH[(nt * 2 + 1) * 512 + ln * 8];
#pragma unroll
        for (int pe = 0; pe < 2; pe++) {
          f32x4 a = g ? gi2[pe] : gr[pe];
          a = mfma_bf16(ai[pe][0], wi0, a);
          a = mfma_bf16(ai[pe][1], wi1, a);
          a = mfma_bf16(ah[pe][0], wh0, a);
          a = mfma_bf16(ah[pe][1], wh1, a);
          if (g) gi2[pe] = a; else gr[pe] = a;
        }
      }
      {
        int nt = 8 + ot;
        bf16x8 wi0 = *(const bf16x8*)&GI[(nt * 2 + 0) * 512 + ln * 8];
        bf16x8 wi1 = *(const bf16x8*)&GI[(nt * 2 + 1) * 512 + ln * 8];
        bf16x8 wh0 = *(const bf16x8*)&GH[(nt * 2 + 0) * 512 + ln * 8];
        bf16x8 wh1 = *(const bf16x8*)&GH[(nt * 2 + 1) * 512 + ln * 8];
#pragma unroll
        for (int pe = 0; pe < 2; pe++) {
          gni2[pe] = mfma_bf16(ai[pe][0], wi0, gni2[pe]);
          gni2[pe] = mfma_bf16(ai[pe][1], wi1, gni2[pe]);
          gnh2[pe] = mfma_bf16(ah[pe][0], wh0, gnh2[pe]);
          gnh2[pe] = mfma_bf16(ah[pe][1], wh1, gnh2[pe]);
        }
      }
      int o = ot * 16 + l16;
      float bir = gbi[o],       bhr = gbh[o];
      float bii = gbi[64 + o],  bhi = gbh[64 + o];
      float bin = gbi[128 + o], bhn = gbh[128 + o];
#pragma unroll
      for (int pe = 0; pe < 2; pe++)
#pragma unroll
        for (int r = 0; r < 4; r++) {
          int b = rg * 16 + quad * 4 + r;
          float xr = gr[pe][r]   + bir + bhr;
          float xi = gi2[pe][r]  + bii + bhi;
          float xn = gni2[pe][r] + bin;
          float hn = gnh2[pe][r] + bhn;
          float rgt = sigm(xr);
          float ig  = sigm(xi);
          float ng  = tanh_f(xn + rgt * hn);
          float hv  = (float)Hh[pe][b][o];
          hedW[(e0 + pe) * 4096 + b * 64 + o] =
              (bf16)((1.0f - ig) * ng + ig * hv);
        }
    }
  }
}

// ---------------------------------------------------------------------------
// Node body v2 (R14-validated): gate-aligned GRU, gates finished in registers.
// Works at 384 (solo) and 512 (fused) threads. smem carve = 30208 B.
// ---------------------------------------------------------------------------
__device__ __forceinline__ void node_body(
    char* smem, int nq, int tid,
    const float* __restrict__ x, const bf16* __restrict__ hed,
    float* __restrict__ xf, bf16* __restrict__ xb, float* __restrict__ hnode,
    const bf16* __restrict__ GN,
    const float* __restrict__ gnbi, const float* __restrict__ gnbh,
    const bf16* __restrict__ OW1, const float* __restrict__ ob1,
    const bf16* __restrict__ OW2, const float* __restrict__ ob2,
    const bf16* __restrict__ OW3, const float* __restrict__ ob3,
    float* __restrict__ out, int t) {
  float (*aggf)[64] = (float(*)[64])(smem);            // 4096
  float (*xinf)[32] = (float(*)[32])(smem + 4096);     // 2048
  float (*hvf)[96]  = (float(*)[96])(smem + 6144);     // 6144
  bf16  (*c0b)[112] = (bf16(*)[112])(smem + 12288);    // 3584
  bf16  (*hvb)[112] = (bf16(*)[112])(smem + 15872);    // 3584
  bf16  (*cnb)[112] = (bf16(*)[112])(smem + 19456);    // 3584
  bf16  (*s1b)[112] = (bf16(*)[112])(smem + 23040);    // 3584
  bf16  (*s2b)[112] = (bf16(*)[112])(smem + 26624);    // 3584 -> 30208
  int n = nq >> 2, q = nq & 3;
  int wv = tid >> 6, ln = tid & 63, quad = ln >> 4, l16 = ln & 15;
  if (tid < 256) {
    int r = tid >> 4, o4 = tid & 15;
    const bf16x4* bp = (const bf16x4*)hed + (size_t)n * 31 * 1024 + (q * 16 + r) * 16 + o4;
    float sx = 0.f, sy = 0.f, sz = 0.f, sw = 0.f;
#pragma unroll
    for (int e2 = 0; e2 < 31; e2++) {
      bf16x4 v = bp[e2 * 1024];
      sx += (float)v[0]; sy += (float)v[1]; sz += (float)v[2]; sw += (float)v[3];
    }
    const float inv = 1.0f / 31.0f;
    sx *= inv; sy *= inv; sz *= inv; sw *= inv;
    int o = o4 * 4;
    aggf[r][o] = sx; aggf[r][o + 1] = sy; aggf[r][o + 2] = sz; aggf[r][o + 3] = sw;
    c0b[r][32 + o] = (bf16)sx; c0b[r][33 + o] = (bf16)sy;
    c0b[r][34 + o] = (bf16)sz; c0b[r][35 + o] = (bf16)sw;
  }
  if (tid < 128) {
    int r = tid >> 3, d0 = (tid & 7) * 4;
    int b = q * 16 + r;
#pragma unroll
    for (int k = 0; k < 4; k++) {
      float v = xf[n * 2048 + b * 32 + d0 + k];
      xinf[r][d0 + k] = v;
      c0b[r][d0 + k] = (bf16)v;
    }
  }
  if (t > 0 && tid < 256) {
    int r = tid >> 4, cb = (tid & 15) * 6;
    int row = n * 64 + q * 16 + r;
#pragma unroll
    for (int k = 0; k < 6; k++) {
      float v = hnode[row * 96 + cb + k];
      hvf[r][cb + k] = v;
      hvb[r][cb + k] = (bf16)v;
    }
  }
  __syncthreads();
  if (t > 0 && wv < 6) {
    int ct = wv;
    bf16x8 a0[3], a1[3];
#pragma unroll
    for (int kf = 0; kf < 3; kf++) {
      a0[kf] = *(const bf16x8*)&c0b[l16][kf * 32 + quad * 8];
      a1[kf] = *(const bf16x8*)&hvb[l16][kf * 32 + quad * 8];
    }
    const bf16* W0 = GN;
    const bf16* W1 = GN + 27648;
    f32x4 aR = {0.f,0.f,0.f,0.f}, bR = {0.f,0.f,0.f,0.f};
    f32x4 aI = {0.f,0.f,0.f,0.f}, bI = {0.f,0.f,0.f,0.f};
    f32x4 aN = {0.f,0.f,0.f,0.f}, bN = {0.f,0.f,0.f,0.f};
#pragma unroll
    for (int kf = 0; kf < 3; kf++) {
      int ir = ((ct * 3 + kf) * 64 + ln) * 8;
      int ii = (((6 + ct) * 3 + kf) * 64 + ln) * 8;
      int in_ = (((12 + ct) * 3 + kf) * 64 + ln) * 8;
      aR = mfma_bf16(a0[kf], *(const bf16x8*)&W0[ir],  aR);
      bR = mfma_bf16(a1[kf], *(const bf16x8*)&W1[ir],  bR);
      aI = mfma_bf16(a0[kf], *(const bf16x8*)&W0[ii],  aI);
      bI = mfma_bf16(a1[kf], *(const bf16x8*)&W1[ii],  bI);
      aN = mfma_bf16(a0[kf], *(const bf16x8*)&W0[in_], aN);
      bN = mfma_bf16(a1[kf], *(const bf16x8*)&W1[in_], bN);
    }
    int col = ct * 16 + l16;
    float bRc = gnbi[col] + gnbh[col];
    float bIc = gnbi[96 + col] + gnbh[96 + col];
    float bN0 = gnbi[192 + col], bN1 = gnbh[192 + col];
    int rowbase = n * 64 + q * 16;
#pragma unroll
    for (int rr = 0; rr < 4; rr++) {
      int row = quad * 4 + rr;
      float xr = aR[rr] + bR[rr] + bRc;
      float xi = aI[rr] + bI[rr] + bIc;
      float xn = aN[rr] + bN0;
      float hn = bN[rr] + bN1;
      float rg = sigm(xr);
      float ig = sigm(xi);
      float ng = tanh_f(xn + rg * hn);
      float v = (1.0f - ig) * ng + ig * hvf[row][col];
      cnb[row][col] = (bf16)v;
      hnode[(rowbase + row) * 96 + col] = v;
    }
  }
  if (t == 0 && tid < 256) {
    int r = tid >> 4, cb = (tid & 15) * 6;
    int row = n * 64 + q * 16 + r;
#pragma unroll
    for (int k = 0; k < 6; k++) {
      int c = cb + k;
      float v = (c < 32) ? xinf[r][c] : aggf[r][c - 32];
      cnb[r][c] = (bf16)v;
      hnode[row * 96 + c] = v;
    }
  }
  __syncthreads();
  if (wv < 4) {
    bf16x8 af3[3];
#pragma unroll
    for (int kf = 0; kf < 3; kf++)
      af3[kf] = *(const bf16x8*)&cnb[l16][kf * 32 + quad * 8];
    f32x4 accn = {0.f, 0.f, 0.f, 0.f};
#pragma unroll
    for (int kf = 0; kf < 3; kf++) {
      bf16x8 bfrag = *(const bf16x8*)&OW1[((wv * 3 + kf) * 64 + ln) * 8];
      accn = mfma_bf16(af3[kf], bfrag, accn);
    }
    int col = wv * 16 + l16;
    float bias = ob1[col];
#pragma unroll
    for (int rr = 0; rr < 4; rr++) {
      float vv = accn[rr] + bias;
      s1b[quad * 4 + rr][col] = (bf16)(vv > 0.f ? vv : 0.f);
    }
  }
  __syncthreads();
  if (wv < 4) {
    bf16x8 af2[2];
#pragma unroll
    for (int kf = 0; kf < 2; kf++)
      af2[kf] = *(const bf16x8*)&s1b[l16][kf * 32 + quad * 8];
    f32x4 accn = {0.f, 0.f, 0.f, 0.f};
#pragma unroll
    for (int kf = 0; kf < 2; kf++) {
      bf16x8 bfrag = *(const bf16x8*)&OW2[((wv * 2 + kf) * 64 + ln) * 8];
      accn = mfma_bf16(af2[kf], bfrag, accn);
    }
    int col = wv * 16 + l16;
    float bias = ob2[col];
#pragma unroll
    for (int rr = 0; rr < 4; rr++) {
      float vv = accn[rr] + bias;
      s2b[quad * 4 + rr][col] = (bf16)(vv > 0.f ? vv : 0.f);
    }
  }
  __syncthreads();
  if (wv < 2) {
    bf16x8 af2[2];
#pragma unroll
    for (int kf = 0; kf < 2; kf++)
      af2[kf] = *(const bf16x8*)&s2b[l16][kf * 32 + quad * 8];
    f32x4 accn = {0.f, 0.f, 0.f, 0.f};
#pragma unroll
    for (int kf = 0; kf < 2; kf++) {
      bf16x8 bfrag = *(const bf16x8*)&OW3[((wv * 2 + kf) * 64 + ln) * 8];
      accn = mfma_bf16(af2[kf], bfrag, accn);
    }
    int d = wv * 16 + l16;
    float bias = ob3[d];
#pragma unroll
    for (int rr = 0; rr < 4; rr++) {
      int r = quad * 4 + rr;
      int b = q * 16 + r;
      float xm = xinf[r][d] + accn[rr] + bias;
      int base = (b * 32 + n) * 32 + d;
      out[524288 + base * 16 + t] = xm;
      out[1572864 + base * 16 + t] = xm;
      if (t >= NSTEP) out[base * 8 + (t - NSTEP)] = xm;
      float vnext = (t + 1 < NSTEP) ? x[base * 8 + (t + 1)] : xm;
      xf[n * 2048 + b * 32 + d] = vnext;
      xb[n * 2048 + b * 32 + d] = (bf16)vnext;
    }
  }
}

// ---------------------------------------------------------------------------
// Kernels: solo edge, solo node (384 thr), fused [node(t-1) || edge(t)]
// (t = 1..7). NO spin-gating (R11), NO grid fences (R2), Hh staged (R15).
// ---------------------------------------------------------------------------
__global__ __launch_bounds__(512, 4) void edge_step(
    const bf16* __restrict__ xsrc, const int* __restrict__ es,
    const float* __restrict__ z,
    const bf16* __restrict__ B1, const bf16* __restrict__ B2,
    const float* __restrict__ mb1, const float* __restrict__ mb2,
    const bf16* __restrict__ GI, const bf16* __restrict__ GH,
    const float* __restrict__ gbi, const float* __restrict__ gbh,
    const bf16* __restrict__ hedR, bf16* __restrict__ hedW, int t) {
  __shared__ __align__(16) char smem[71168];
  edge_body(smem, blockIdx.x * 2, threadIdx.x, xsrc, es, z, B1, B2, mb1, mb2,
            GI, GH, gbi, gbh, hedR, hedW, t);
}

__global__ __launch_bounds__(384) void node_kernel(
    const float* __restrict__ x, const bf16* __restrict__ hed,
    float* __restrict__ xf, bf16* __restrict__ xb, float* __restrict__ hnode,
    const bf16* __restrict__ GN,
    const float* __restrict__ gnbi, const float* __restrict__ gnbh,
    const bf16* __restrict__ OW1, const float* __restrict__ ob1,
    const bf16* __restrict__ OW2, const float* __restrict__ ob2,
    const bf16* __restrict__ OW3, const float* __restrict__ ob3,
    float* __restrict__ out, int t) {
  __shared__ __align__(16) char smem[30208];
  node_body(smem, blockIdx.x, threadIdx.x, x, hed, xf, xb, hnode, GN,
            gnbi, gnbh, OW1, ob1, OW2, ob2, OW3, ob3, out, t);
}

__global__ __launch_bounds__(512, 4) void fused_ne(
    const float* __restrict__ x,
    const bf16* __restrict__ xsrc, const int* __restrict__ es,
    const float* __restrict__ z,
    const bf16* __restrict__ B1, const bf16* __restrict__ B2,
    const float* __restrict__ mb1, const float* __restrict__ mb2,
    const bf16* __restrict__ GI, const bf16* __restrict__ GH,
    const float* __restrict__ gbi, const float* __restrict__ gbh,
    const bf16* __restrict__ hedR, bf16* __restrict__ hedW,
    float* __restrict__ xf, bf16* __restrict__ xb, float* __restrict__ hnode,
    const bf16* __restrict__ GN,
    const float* __restrict__ gnbi, const float* __restrict__ gnbh,
    const bf16* __restrict__ OW1, const float* __restrict__ ob1,
    const bf16* __restrict__ OW2, const float* __restrict__ ob2,
    const bf16* __restrict__ OW3, const float* __restrict__ ob3,
    float* __restrict__ out, int te) {
  __shared__ __align__(16) char smem[71168];
  if (blockIdx.x < 128) {
    node_body(smem, blockIdx.x, threadIdx.x, x, hedR, xf, xb, hnode, GN,
              gnbi, gnbh, OW1, ob1, OW2, ob2, OW3, ob3, out, te - 1);
  } else {
    edge_body(smem, (blockIdx.x - 128) * 2, threadIdx.x, xsrc, es, z, B1, B2,
              mb1, mb2, GI, GH, gbi, gbh, hedR, hedW, te);
  }
}

extern "C" void kernel_launch(void* const* d_in, const int* in_sizes, int n_in,
                              void* d_out, int out_size, void* d_ws, size_t ws_size,
                              hipStream_t stream) {
  const float* x     = (const float*)d_in[0];
  const float* z     = (const float*)d_in[1];
  const int*   es    = (const int*)d_in[2];
  const float* msgW1 = (const float*)d_in[6];
  const float* msgb1 = (const float*)d_in[7];
  const float* msgW2 = (const float*)d_in[8];
  const float* msgb2 = (const float*)d_in[9];
  const float* oW1   = (const float*)d_in[10];
  const float* ob1   = (const float*)d_in[11];
  const float* oW2   = (const float*)d_in[12];
  const float* ob2   = (const float*)d_in[13];
  const float* oW3   = (const float*)d_in[14];
  const float* ob3   = (const float*)d_in[15];
  const float* geWi  = (const float*)d_in[16];
  const float* gebi  = (const float*)d_in[17];
  const float* geWh  = (const float*)d_in[18];
  const float* gebh  = (const float*)d_in[19];
  const float* gnWi  = (const float*)d_in[20];
  const float* gnbi  = (const float*)d_in[21];
  const float* gnWh  = (const float*)d_in[22];
  const float* gnbh  = (const float*)d_in[23];
  float* out = (float*)d_out;

  char* p = (char*)d_ws;
  bf16*  hedA  = (bf16*)p;   p += (size_t)NE * 4096 * 2;   // 8.1 MB
  bf16*  hedB  = (bf16*)p;   p += (size_t)NE * 4096 * 2;   // 8.1 MB
  bf16*  xball = (bf16*)p;   p += (size_t)8 * 65536 * 2;   // 1 MB
  float* xf    = (float*)p;  p += 65536 * 4;
  bf16*  xb    = (bf16*)p;   p += 65536 * 2;
  float* hnode = (float*)p;  p += 196608 * 4;
  bf16*  B1sw  = (bf16*)p;   p += 12288 * 2;
  bf16*  B2sw  = (bf16*)p;   p += 12288 * 2;
  bf16*  GIsw  = (bf16*)p;   p += 12288 * 2;
  bf16*  GHsw  = (bf16*)p;   p += 12288 * 2;
  bf16*  GNsw  = (bf16*)p;   p += 55296 * 2;
  bf16*  OW1s  = (bf16*)p;   p += 6144 * 2;
  bf16*  OW2s  = (bf16*)p;   p += 4096 * 2;
  bf16*  OW3s  = (bf16*)p;   p += 2048 * 2;

  bf16* hbuf[2] = {hedA, hedB};

  prep_weights<<<204, 256, 0, stream>>>(msgW1, msgW2, geWi, geWh, gnWi, gnWh,
                                        oW1, oW2, oW3,
                                        B1sw, B2sw, GIsw, GHsw, GNsw,
                                        OW1s, OW2s, OW3s);
  copy_x<<<256, 256, 0, stream>>>(x, xf, xball);

  // t = 0: edge only
  edge_step<<<NE / 2, 512, 0, stream>>>(xball, es, z, B1sw, B2sw, msgb1, msgb2,
                                        GIsw, GHsw, gebi, gebh,
                                        hbuf[1], hbuf[0], 0);
  // t = 1..7: fused [node(t-1) || edge(t)] — edge input is ground-truth x
  for (int t = 1; t < NSTEP; t++) {
    fused_ne<<<128 + NE / 2, 512, 0, stream>>>(
        x, xball + (size_t)t * 65536, es, z, B1sw, B2sw, msgb1, msgb2,
        GIsw, GHsw, gebi, gebh,
        hbuf[(t - 1) & 1], hbuf[t & 1],
        xf, xb, hnode, GNsw, gnbi, gnbh,
        OW1s, ob1, OW2s, ob2, OW3s, ob3, out, t);
  }
  // node(7) (produces xb for t=8), then serial for the feedback phase
  node_kernel<<<128, 384, 0, stream>>>(x, hbuf[(NSTEP - 1) & 1], xf, xb, hnode,
                                       GNsw, gnbi, gnbh, OW1s, ob1, OW2s, ob2,
                                       OW3s, ob3, out, NSTEP - 1);
  for (int t = NSTEP; t < NTT; t++) {
    edge_step<<<NE / 2, 512, 0, stream>>>(xb, es, z, B1sw, B2sw, msgb1, msgb2,
                                          GIsw, GHsw, gebi, gebh,
                                          hbuf[(t - 1) & 1], hbuf[t & 1], t);
    node_kernel<<<128, 384, 0, stream>>>(x, hbuf[t & 1], xf, xb, hnode,
                                         GNsw, gnbi, gnbh, OW1s, ob1, OW2s, ob2,
                                         OW3s, ob3, out, t);
  }
}